// Round 3
// baseline (150.100 us; speedup 1.0000x reference)
//
#include <hip/hip_runtime.h>

// anchors: (8192, 8, 768) fp32 = [n=8192 rows][COLS=6144 cols]
// loss = -((2*n*sum(a^2) - 2*dot(colsum, colsum)) / sqrt(768)) / (8*8)
//
// Single fused kernel: grid of 6 column-strips x 128 row-chunks accumulates
// per-column partial sums (fp32 atomics into ws) + global sum-of-squares;
// the LAST block to finish (device-scope counter) computes dot(colsum,colsum)
// and writes the scalar loss. Agent-scope atomic loads for the final reads
// (per-XCD L2s are not coherent).

typedef float f32x4 __attribute__((ext_vector_type(4)));

constexpr int COLS   = 6144;       // k * dim_emb = 8 * 768
constexpr int COLS4  = COLS / 4;   // 1536 float4 per row
constexpr int BLK    = 256;
constexpr int STRIPS = COLS4 / BLK;        // 6 column strips
constexpr int ROWS_PER_CHUNK = 64;

__global__ void __launch_bounds__(BLK)
anchor_fused(const f32x4* __restrict__ a,
             float* __restrict__ col_sum,     // ws[0..COLS)
             float* __restrict__ sum_sq,      // ws[COLS]
             unsigned* __restrict__ counter,  // ws[COLS+1]
             float* __restrict__ out, int n_rows) {
    const int col4 = blockIdx.x * BLK + threadIdx.x;   // 0..COLS4-1
    const int row0 = blockIdx.y * ROWS_PER_CHUNK;
    const f32x4* p = a + (size_t)row0 * COLS4 + col4;
    const unsigned nblocks = gridDim.x * gridDim.y;

    f32x4 cs = (f32x4)(0.f);
    float ssq = 0.f;
    #pragma unroll 8
    for (int r = 0; r < ROWS_PER_CHUNK; ++r) {
        f32x4 v = __builtin_nontemporal_load(&p[(size_t)r * COLS4]);
        cs += v;
        ssq = fmaf(v.x, v.x, ssq);
        ssq = fmaf(v.y, v.y, ssq);
        ssq = fmaf(v.z, v.z, ssq);
        ssq = fmaf(v.w, v.w, ssq);
    }

    float* c = col_sum + col4 * 4;
    atomicAdd(c + 0, cs.x);
    atomicAdd(c + 1, cs.y);
    atomicAdd(c + 2, cs.z);
    atomicAdd(c + 3, cs.w);

    // block-reduce ssq -> one atomic per block
    #pragma unroll
    for (int off = 32; off > 0; off >>= 1)
        ssq += __shfl_down(ssq, off, 64);
    __shared__ float wsum[BLK / 64];
    const int lane = threadIdx.x & 63, wid = threadIdx.x >> 6;
    if (lane == 0) wsum[wid] = ssq;
    __syncthreads();
    if (threadIdx.x == 0) {
        float s = 0.f;
        #pragma unroll
        for (int w = 0; w < BLK / 64; ++w) s += wsum[w];
        atomicAdd(sum_sq, s);
    }

    // ---- last-block final reduction ----
    __threadfence();                       // release our atomics
    __shared__ int is_last;
    if (threadIdx.x == 0) {
        unsigned prev = atomicAdd(counter, 1u);
        is_last = (prev == nblocks - 1);
    }
    __syncthreads();
    if (!is_last) return;
    __threadfence();                       // acquire others' atomics

    float acc = 0.f;
    for (int i = threadIdx.x; i < COLS; i += BLK) {
        float v = __hip_atomic_load(&col_sum[i], __ATOMIC_RELAXED,
                                    __HIP_MEMORY_SCOPE_AGENT);
        acc = fmaf(v, v, acc);
    }
    #pragma unroll
    for (int off = 32; off > 0; off >>= 1)
        acc += __shfl_down(acc, off, 64);
    if (lane == 0) wsum[wid] = acc;
    __syncthreads();
    if (threadIdx.x == 0) {
        float dot = 0.f;
        #pragma unroll
        for (int w = 0; w < BLK / 64; ++w) dot += wsum[w];
        float s = __hip_atomic_load(sum_sq, __ATOMIC_RELAXED,
                                    __HIP_MEMORY_SCOPE_AGENT);
        double pair = 2.0 * (double)n_rows * (double)s - 2.0 * (double)dot;
        const double factor = 27.712812921102035;  // sqrt(768)
        out[0] = (float)(-(pair / factor) / 64.0); // k*k = 64
    }
}

extern "C" void kernel_launch(void* const* d_in, const int* in_sizes, int n_in,
                              void* d_out, int out_size, void* d_ws, size_t ws_size,
                              hipStream_t stream) {
    const f32x4* a = (const f32x4*)d_in[0];
    float* ws      = (float*)d_ws;
    float* out     = (float*)d_out;
    const int n_rows = in_sizes[0] / COLS;  // 8192

    (void)hipMemsetAsync(d_ws, 0, (COLS + 2) * sizeof(float), stream);

    dim3 grid(STRIPS, n_rows / ROWS_PER_CHUNK);
    anchor_fused<<<grid, BLK, 0, stream>>>(
        a, ws, ws + COLS, (unsigned*)(ws + COLS + 1), out, n_rows);
}

// Round 4
// 62.393 us; speedup vs baseline: 2.4057x; 2.4057x over previous
//
#include <hip/hip_runtime.h>

// anchors: (8192, 8, 768) fp32 = [n=8192 rows][COLS=6144 cols]
// loss = -((2*n*sum(a^2) - 2*dot(colsum, colsum)) / sqrt(768)) / (8*8)
//
// Two-kernel structure (fused last-block version regressed: device-scope
// fences + nt loads broke L3 residency; see R3 post-mortem).
// Input is L3-resident (201 MB < 256 MB LLC) — plain loads, let LLC serve.

typedef float f32x4 __attribute__((ext_vector_type(4)));

constexpr int COLS   = 6144;       // k * dim_emb = 8 * 768
constexpr int COLS4  = COLS / 4;   // 1536 float4 per row
constexpr int BLK    = 256;
constexpr int STRIPS = COLS4 / BLK;        // 6 column strips
constexpr int ROWS_PER_CHUNK = 32;         // 256 chunks -> 1536 blocks (6/CU)

__global__ void __launch_bounds__(BLK)
anchor_pass1(const f32x4* __restrict__ a,
             float* __restrict__ col_sum,   // [COLS]
             float* __restrict__ sum_sq) {  // [1]
    const int col4 = blockIdx.x * BLK + threadIdx.x;   // 0..COLS4-1
    const int row0 = blockIdx.y * ROWS_PER_CHUNK;
    const f32x4* p = a + (size_t)row0 * COLS4 + col4;

    f32x4 cs = (f32x4)(0.f);
    float ssq = 0.f;
    #pragma unroll 8
    for (int r = 0; r < ROWS_PER_CHUNK; ++r) {
        f32x4 v = p[(size_t)r * COLS4];
        cs += v;
        ssq = fmaf(v.x, v.x, ssq);
        ssq = fmaf(v.y, v.y, ssq);
        ssq = fmaf(v.z, v.z, ssq);
        ssq = fmaf(v.w, v.w, ssq);
    }

    float* c = col_sum + col4 * 4;
    atomicAdd(c + 0, cs.x);
    atomicAdd(c + 1, cs.y);
    atomicAdd(c + 2, cs.z);
    atomicAdd(c + 3, cs.w);

    // block-reduce ssq -> one atomic per block
    #pragma unroll
    for (int off = 32; off > 0; off >>= 1)
        ssq += __shfl_down(ssq, off, 64);
    __shared__ float wsum[BLK / 64];
    const int lane = threadIdx.x & 63, wid = threadIdx.x >> 6;
    if (lane == 0) wsum[wid] = ssq;
    __syncthreads();
    if (threadIdx.x == 0) {
        float s = 0.f;
        #pragma unroll
        for (int w = 0; w < BLK / 64; ++w) s += wsum[w];
        atomicAdd(sum_sq, s);
    }
}

__global__ void __launch_bounds__(1024)
anchor_pass2(const float* __restrict__ col_sum,
             const float* __restrict__ sum_sq,
             float* __restrict__ out, int n_rows) {
    float acc = 0.f;
    for (int i = threadIdx.x; i < COLS; i += 1024) {
        float v = col_sum[i];
        acc = fmaf(v, v, acc);
    }
    #pragma unroll
    for (int off = 32; off > 0; off >>= 1)
        acc += __shfl_down(acc, off, 64);
    __shared__ float wsum[1024 / 64];
    const int lane = threadIdx.x & 63, wid = threadIdx.x >> 6;
    if (lane == 0) wsum[wid] = acc;
    __syncthreads();
    if (threadIdx.x == 0) {
        float dot = 0.f;
        #pragma unroll
        for (int w = 0; w < 1024 / 64; ++w) dot += wsum[w];
        double pair = 2.0 * (double)n_rows * (double)(*sum_sq)
                    - 2.0 * (double)dot;
        const double factor = 27.712812921102035;  // sqrt(768)
        out[0] = (float)(-(pair / factor) / 64.0); // k*k = 64
    }
}

extern "C" void kernel_launch(void* const* d_in, const int* in_sizes, int n_in,
                              void* d_out, int out_size, void* d_ws, size_t ws_size,
                              hipStream_t stream) {
    const f32x4* a = (const f32x4*)d_in[0];
    float* ws      = (float*)d_ws;          // [0..COLS): col_sum, [COLS]: sum_sq
    float* out     = (float*)d_out;
    const int n_rows = in_sizes[0] / COLS;  // 8192

    (void)hipMemsetAsync(d_ws, 0, (COLS + 1) * sizeof(float), stream);

    dim3 grid(STRIPS, n_rows / ROWS_PER_CHUNK);
    anchor_pass1<<<grid, BLK, 0, stream>>>(a, ws, ws + COLS);
    anchor_pass2<<<1, 1024, 0, stream>>>(ws, ws + COLS, out, n_rows);
}